// Round 10
// baseline (57058.612 us; speedup 1.0000x reference)
//
#include <hip/hip_runtime.h>
#include <hip/hip_fp16.h>

typedef unsigned short u16;
typedef unsigned int u32;
typedef unsigned long long u64;
typedef signed char i8;

#define E 2048
#define T_STEPS 512
#define NB 256
#define NT 1024

// ---------------- helpers ----------------
__device__ __forceinline__ float4 i8x4_to_f4(u32 v) {
    return make_float4((float)(i8)(v & 0xff), (float)(i8)((v >> 8) & 0xff),
                       (float)(i8)((v >> 16) & 0xff), (float)(i8)((v >> 24) & 0xff));
}
__device__ __forceinline__ float dot4(float4 a, float4 b, float acc) {
    acc = fmaf(a.x, b.x, acc);
    acc = fmaf(a.y, b.y, acc);
    acc = fmaf(a.z, b.z, acc);
    acc = fmaf(a.w, b.w, acc);
    return acc;
}
__device__ __forceinline__ float wred(float t) {
#pragma unroll
    for (int off = 32; off > 0; off >>= 1) t += __shfl_xor(t, off);
    return t;
}
__device__ __forceinline__ float sigm(float v) { return 1.f / (1.f + expf(-v)); }
__device__ __forceinline__ void astf(float* p, float v) {
    __hip_atomic_store((u32*)p, __float_as_uint(v), __ATOMIC_RELAXED,
                       __HIP_MEMORY_SCOPE_AGENT);
}

// ---------------- prep kernels ----------------

// W_comb[r][c] = sum_k W_ih0[r][k] * W_out[k][c]  (fp32 out; 8192 x 2048)
__global__ __launch_bounds__(256) void k_wcomb(const float* __restrict__ wih0,
                                               const float* __restrict__ wout,
                                               float* __restrict__ wc) {
    __shared__ float a[8 * 128];
    int r0 = blockIdx.y * 8;
    int c = blockIdx.x * 256 + threadIdx.x;
    for (int i = threadIdx.x; i < 8 * 128; i += 256) a[i] = wih0[r0 * 128 + i];
    __syncthreads();
    float acc[8] = {0.f, 0.f, 0.f, 0.f, 0.f, 0.f, 0.f, 0.f};
    for (int k = 0; k < 128; ++k) {
        float b = wout[k * E + c];
#pragma unroll
        for (int j = 0; j < 8; ++j) acc[j] = fmaf(a[j * 128 + k], b, acc[j]);
    }
#pragma unroll
    for (int j = 0; j < 8; ++j) wc[(size_t)(r0 + j) * E + c] = acc[j];
}

// per-row int8 quantization of a (4E x E) matrix: one wave per row
__global__ __launch_bounds__(64) void k_quant(const float* __restrict__ in,
                                              i8* __restrict__ q,
                                              float* __restrict__ scales) {
    const int r = blockIdx.x;
    const int l = threadIdx.x;
    const float* row = in + (size_t)r * E;
    float4 v[8];
    float m = 0.f;
#pragma unroll
    for (int u = 0; u < 8; ++u) {
        v[u] = *(const float4*)(row + u * 256 + l * 4);
        m = fmaxf(m, fmaxf(fmaxf(fabsf(v[u].x), fabsf(v[u].y)),
                           fmaxf(fabsf(v[u].z), fabsf(v[u].w))));
    }
#pragma unroll
    for (int off = 32; off > 0; off >>= 1) m = fmaxf(m, __shfl_xor(m, off));
    const float scale = fmaxf(m, 1e-30f) / 127.f;
    const float inv = 127.f / fmaxf(m, 1e-30f);
    i8* qr = q + (size_t)r * E;
#pragma unroll
    for (int u = 0; u < 8; ++u) {
        int a0 = (int)rintf(v[u].x * inv);
        int a1 = (int)rintf(v[u].y * inv);
        int a2 = (int)rintf(v[u].z * inv);
        int a3 = (int)rintf(v[u].w * inv);
        u32 pk = ((u32)(a0 & 0xff)) | ((u32)(a1 & 0xff) << 8) |
                 ((u32)(a2 & 0xff) << 16) | ((u32)(a3 & 0xff) << 24);
        *(u32*)(qr + u * 256 + l * 4) = pk;
    }
    if (l == 0) scales[r] = scale;
}

// W_outT[e][d] = W_out[d][e]
__global__ void k_transpose_wout(const float* __restrict__ wout, float* __restrict__ woutT) {
    int o = blockIdx.x * blockDim.x + threadIdx.x;
    if (o >= E * 128) return;
    int e = o >> 7, d = o & 127;
    woutT[o] = wout[d * E + e];
}

// bcomb[r] = b_ih0[r]+b_hh0[r]+dot(W_ih0[r],b_out);  bias1[r] = b_ih1[r]+b_hh1[r]
__global__ void k_bcomb(const float* __restrict__ wih0, const float* __restrict__ bout,
                        const float* __restrict__ bih0, const float* __restrict__ bhh0,
                        const float* __restrict__ bih1, const float* __restrict__ bhh1,
                        float* __restrict__ bcomb, float* __restrict__ bias1) {
    int r = blockIdx.x * blockDim.x + threadIdx.x;
    if (r >= 4 * E) return;
    float acc = bih0[r] + bhh0[r];
    const float* w = wih0 + (size_t)r * 128;
#pragma unroll 8
    for (int k = 0; k < 128; ++k) acc = fmaf(w[k], bout[k], acc);
    bcomb[r] = acc;
    bias1[r] = bih1[r] + bhh1[r];
}

// h1hist[0] = lat, h0buf slot0 = lat, zero barrier
__global__ void k_init(const float* __restrict__ lat, float* __restrict__ h0buf,
                       float* __restrict__ h1hist, u32* __restrict__ bar) {
    int i = blockIdx.x * blockDim.x + threadIdx.x;
    if (i < 1056) bar[i] = 0;
    if (i >= E) return;
    float v = lat[i];
    h0buf[i] = v;
    h1hist[i] = v;
}

// ---------------- grid barrier ----------------
// arrivals: release fetch_add on 64 spread leaves. wait: RELAXED polls (no L2
// invalidate per poll), then ONE acquire load (single L1/L2 invalidate).
__device__ __forceinline__ void gbar(u32* bar, int b, u32 bcount) {
    __syncthreads();  // drains all block stores (incl. relaxed-atomic h writes)
    if (threadIdx.x == 0)
        __hip_atomic_fetch_add(bar + (b & 63) * 16, 1u, __ATOMIC_RELEASE,
                               __HIP_MEMORY_SCOPE_AGENT);
    if (b == 0) {
        if (threadIdx.x < 64) {
            const u32* leaf = bar + threadIdx.x * 16;
            int tmo = 0;
            while (__hip_atomic_load(leaf, __ATOMIC_RELAXED,
                                     __HIP_MEMORY_SCOPE_AGENT) < 4u * bcount) {
                __builtin_amdgcn_s_sleep(1);
                if (++tmo > (1 << 20)) break;  // safety valve
            }
        }
        __syncthreads();
        if (threadIdx.x == 0)
            __hip_atomic_store(bar + 1024, bcount, __ATOMIC_RELEASE,
                               __HIP_MEMORY_SCOPE_AGENT);
    } else {
        if (threadIdx.x == 0) {
            int tmo = 0;
            while (__hip_atomic_load(bar + 1024, __ATOMIC_RELAXED,
                                     __HIP_MEMORY_SCOPE_AGENT) < bcount) {
                __builtin_amdgcn_s_sleep(2);
                if (++tmo > (1 << 20)) break;  // safety valve
            }
        }
    }
    // one acquire: invalidates this CU's L1 + XCD L2 so following normal loads
    // observe other XCDs' writes via IC
    if (threadIdx.x == 0)
        (void)__hip_atomic_load(bar + 1024, __ATOMIC_ACQUIRE,
                                __HIP_MEMORY_SCOPE_AGENT);
    __syncthreads();
}

// ---------------- persistent kernel: 511 steps, 2 barriers/step, weights in regs ----
__global__ __launch_bounds__(NT, 4) void k_persist(
    const u32* __restrict__ Qc, const float* __restrict__ sC,
    const u32* __restrict__ Qh0, const float* __restrict__ sH0,
    const u32* __restrict__ Qi1, const float* __restrict__ sI1,
    const u32* __restrict__ Qh1, const float* __restrict__ sH1,
    const float* __restrict__ bcomb, const float* __restrict__ bias1,
    float* __restrict__ h0buf, float* __restrict__ h1hist, u32* __restrict__ bar) {
    const int b = blockIdx.x;
    const int tid = threadIdx.x;
    const int w = tid >> 6, l = tid & 63;

    __shared__ float h1s[E], h0s[E];
    __shared__ float gl[32];
    __shared__ float c0s[8], c1s[8];

    // rows for this wave: r = w*2+k in [0,32); gate q=r>>3, elem i=r&7
    int rows[2];
    rows[0] = ((w * 2) >> 3) * E + b * 8 + ((w * 2) & 7);
    rows[1] = ((w * 2 + 1) >> 3) * E + b * 8 + ((w * 2 + 1) & 7);
    u32 wC[2][8], wH0[2][8], wI1[2][8], wH1[2][8];
    float sCr[2], sH0r[2], sI1r[2], sH1r[2];
#pragma unroll
    for (int k = 0; k < 2; ++k) {
        const size_t rb = (size_t)rows[k] * 512;  // u32 units
#pragma unroll
        for (int j = 0; j < 8; ++j) {
            wC[k][j] = Qc[rb + j * 64 + l];
            wH0[k][j] = Qh0[rb + j * 64 + l];
            wI1[k][j] = Qi1[rb + j * 64 + l];
            wH1[k][j] = Qh1[rb + j * 64 + l];
        }
        sCr[k] = sC[rows[k]];
        sH0r[k] = sH0[rows[k]];
        sI1r[k] = sI1[rows[k]];
        sH1r[k] = sH1[rows[k]];
    }
    if (tid < 8) { c0s[tid] = 0.f; c1s[tid] = 0.f; }

    // pre-loop: stage h0(0) (persists in LDS across steps; re-staged each phase B)
    ((u64*)h0s)[tid] = ((const u64*)h0buf)[tid];

    u32 bcount = 0;
    for (int s = 1; s < T_STEPS; ++s) {
        const int cp = s & 1;

        // stage h1(s-1) (normal coalesced loads; L2 invalidated at last barrier)
        ((u64*)h1s)[tid] = ((const u64*)(h1hist + (size_t)(s - 1) * E))[tid];
        __syncthreads();

        // phase A: gates0 = Wcomb@h1(s-1) + Whh0@h0(s-1)
#pragma unroll
        for (int k = 0; k < 2; ++k) {
            float aC = 0.f, aH = 0.f;
#pragma unroll
            for (int j = 0; j < 8; ++j) {
                float4 v1 = *(const float4*)&h1s[4 * (j * 64 + l)];
                float4 v0 = *(const float4*)&h0s[4 * (j * 64 + l)];
                aC = dot4(i8x4_to_f4(wC[k][j]), v1, aC);
                aH = dot4(i8x4_to_f4(wH0[k][j]), v0, aH);
            }
            float t = wred(aC * sCr[k] + aH * sH0r[k]);
            if (l == 0) gl[w * 2 + k] = t;
        }
        __syncthreads();
        if (tid < 8) {
            const int e = b * 8 + tid;
            float gi = gl[tid] + bcomb[e];
            float gf = gl[8 + tid] + bcomb[E + e];
            float gg = gl[16 + tid] + bcomb[2 * E + e];
            float go = gl[24 + tid] + bcomb[3 * E + e];
            float cn = fmaf(sigm(gf), c0s[tid], sigm(gi) * tanhf(gg));
            c0s[tid] = cn;
            astf(&h0buf[cp * E + e], sigm(go) * tanhf(cn));
        }
        ++bcount;
        gbar(bar, b, bcount);

        // stage h0(s) (stays resident for next step's phase A)
        ((u64*)h0s)[tid] = ((const u64*)(h0buf + cp * E))[tid];
        __syncthreads();

        // phase B: gates1 = Qih1@h0(s) + Qhh1@h1(s-1)   (h1s still staged)
#pragma unroll
        for (int k = 0; k < 2; ++k) {
            float aI = 0.f, aH = 0.f;
#pragma unroll
            for (int j = 0; j < 8; ++j) {
                float4 v0 = *(const float4*)&h0s[4 * (j * 64 + l)];
                float4 v1 = *(const float4*)&h1s[4 * (j * 64 + l)];
                aI = dot4(i8x4_to_f4(wI1[k][j]), v0, aI);
                aH = dot4(i8x4_to_f4(wH1[k][j]), v1, aH);
            }
            float t = wred(aI * sI1r[k] + aH * sH1r[k]);
            if (l == 0) gl[w * 2 + k] = t;
        }
        __syncthreads();
        if (tid < 8) {
            const int e = b * 8 + tid;
            float gi = gl[tid] + bias1[e];
            float gf = gl[8 + tid] + bias1[E + e];
            float gg = gl[16 + tid] + bias1[2 * E + e];
            float go = gl[24 + tid] + bias1[3 * E + e];
            float cn = fmaf(sigm(gf), c1s[tid], sigm(gi) * tanhf(gg));
            c1s[tid] = cn;
            astf(&h1hist[(size_t)s * E + e], sigm(go) * tanhf(cn));
        }
        if (s < T_STEPS - 1) {
            ++bcount;
            gbar(bar, b, bcount);
        }
    }
}

// ---------------- final output GEMM: out[t] = Wout @ h1hist[t] + bout ----------------
__global__ __launch_bounds__(128) void k_out(const float* __restrict__ woutT,
                                             const float* __restrict__ hist,
                                             const float* __restrict__ bout,
                                             float* __restrict__ out) {
    __shared__ float h[E];
    int t = blockIdx.x, d = threadIdx.x;
    for (int i = d; i < E; i += 128) h[i] = hist[(size_t)t * E + i];
    __syncthreads();
    float acc0 = bout[d], acc1 = 0.f;
#pragma unroll 4
    for (int k = 0; k < E; k += 2) {
        acc0 = fmaf(woutT[k * 128 + d], h[k], acc0);
        acc1 = fmaf(woutT[(k + 1) * 128 + d], h[k + 1], acc1);
    }
    out[t * 128 + d] = acc0 + acc1;
}

extern "C" void kernel_launch(void* const* d_in, const int* in_sizes, int n_in,
                              void* d_out, int out_size, void* d_ws, size_t ws_size,
                              hipStream_t stream) {
    const float* lat = (const float*)d_in[0];
    const float* wih0 = (const float*)d_in[1];
    const float* whh0 = (const float*)d_in[2];
    const float* bih0 = (const float*)d_in[3];
    const float* bhh0 = (const float*)d_in[4];
    const float* wih1 = (const float*)d_in[5];
    const float* whh1 = (const float*)d_in[6];
    const float* bih1 = (const float*)d_in[7];
    const float* bhh1 = (const float*)d_in[8];
    const float* wout = (const float*)d_in[9];
    const float* bout = (const float*)d_in[10];

    const size_t QB = (size_t)4 * E * E;  // 16.78 MB int8
    char* p = (char*)d_ws;
    i8* Qc = (i8*)p;   p += QB;
    i8* Qh0 = (i8*)p;  p += QB;
    i8* Qi1 = (i8*)p;  p += QB;
    i8* Qh1 = (i8*)p;  p += QB;
    float* sC = (float*)p;  p += (size_t)4 * E * 4;
    float* sH0 = (float*)p; p += (size_t)4 * E * 4;
    float* sI1 = (float*)p; p += (size_t)4 * E * 4;
    float* sH1 = (float*)p; p += (size_t)4 * E * 4;
    float* WcF = (float*)p; p += (size_t)4 * E * E * 4;  // 67 MB temp
    float* woutT = (float*)p; p += (size_t)E * 128 * 4;
    float* bcomb = (float*)p; p += (size_t)4 * E * 4;
    float* bias1 = (float*)p; p += (size_t)4 * E * 4;
    float* h0buf = (float*)p; p += (size_t)2 * E * 4;
    float* h1hist = (float*)p; p += (size_t)T_STEPS * E * 4;
    u32* bar = (u32*)p;       p += 1056 * 4;

    k_wcomb<<<dim3(8, 1024), 256, 0, stream>>>(wih0, wout, WcF);
    k_quant<<<4 * E, 64, 0, stream>>>(WcF, Qc, sC);
    k_quant<<<4 * E, 64, 0, stream>>>(whh0, Qh0, sH0);
    k_quant<<<4 * E, 64, 0, stream>>>(wih1, Qi1, sI1);
    k_quant<<<4 * E, 64, 0, stream>>>(whh1, Qh1, sH1);
    k_transpose_wout<<<(E * 128 + 255) / 256, 256, 0, stream>>>(wout, woutT);
    k_bcomb<<<(4 * E + 255) / 256, 256, 0, stream>>>(wih0, bout, bih0, bhh0, bih1, bhh1,
                                                     bcomb, bias1);
    k_init<<<(E + 255) / 256, 256, 0, stream>>>(lat, h0buf, h1hist, bar);

    k_persist<<<NB, NT, 0, stream>>>((const u32*)Qc, sC, (const u32*)Qh0, sH0,
                                     (const u32*)Qi1, sI1, (const u32*)Qh1, sH1,
                                     bcomb, bias1, h0buf, h1hist, bar);

    k_out<<<T_STEPS, 128, 0, stream>>>(woutT, h1hist, bout, (float*)d_out);
}

// Round 11
// 10831.705 us; speedup vs baseline: 5.2677x; 5.2677x over previous
//
#include <hip/hip_runtime.h>
#include <hip/hip_fp16.h>

typedef unsigned short u16;
typedef unsigned int u32;
typedef signed char i8;

#define E 2048
#define T_STEPS 512

// ---------------- helpers ----------------
__device__ __forceinline__ u32 packh2(float a, float b) {
    return (u32)__half_as_ushort(__float2half_rn(a)) |
           ((u32)__half_as_ushort(__float2half_rn(b)) << 16);
}
__device__ __forceinline__ float hlo(u32 u) {
    return __half2float(__ushort_as_half((u16)(u & 0xffffu)));
}
__device__ __forceinline__ float hhi(u32 u) {
    return __half2float(__ushort_as_half((u16)(u >> 16)));
}
__device__ __forceinline__ float4 i8x4_to_f4(u32 v) {
    return make_float4((float)(i8)(v & 0xff), (float)(i8)((v >> 8) & 0xff),
                       (float)(i8)((v >> 16) & 0xff), (float)(i8)((v >> 24) & 0xff));
}
__device__ __forceinline__ float dot4(float4 a, float4 b, float acc) {
    acc = fmaf(a.x, b.x, acc);
    acc = fmaf(a.y, b.y, acc);
    acc = fmaf(a.z, b.z, acc);
    acc = fmaf(a.w, b.w, acc);
    return acc;
}
__device__ __forceinline__ float wred(float t) {
#pragma unroll
    for (int off = 32; off > 0; off >>= 1) t += __shfl_xor(t, off);
    return t;
}

// ---------------- prep kernels ----------------

__global__ __launch_bounds__(256) void k_cvt_f16(const float* __restrict__ in,
                                                 u16* __restrict__ out, int n8) {
    int i = blockIdx.x * blockDim.x + threadIdx.x;
    if (i >= n8) return;
    const float4* p = (const float4*)in + (size_t)i * 2;
    float4 a = p[0], b = p[1];
    uint4 r;
    r.x = packh2(a.x, a.y);
    r.y = packh2(a.z, a.w);
    r.z = packh2(b.x, b.y);
    r.w = packh2(b.z, b.w);
    ((uint4*)out)[i] = r;
}

// per-row int8 quantization of a (4E x E) matrix: one wave per row
__global__ __launch_bounds__(64) void k_quant(const float* __restrict__ in,
                                              i8* __restrict__ q,
                                              float* __restrict__ scales) {
    const int r = blockIdx.x;
    const int l = threadIdx.x;
    const float* row = in + (size_t)r * E;
    float4 v[8];
    float m = 0.f;
#pragma unroll
    for (int u = 0; u < 8; ++u) {
        v[u] = *(const float4*)(row + u * 256 + l * 4);
        m = fmaxf(m, fmaxf(fmaxf(fabsf(v[u].x), fabsf(v[u].y)),
                           fmaxf(fabsf(v[u].z), fabsf(v[u].w))));
    }
#pragma unroll
    for (int off = 32; off > 0; off >>= 1) m = fmaxf(m, __shfl_xor(m, off));
    const float scale = fmaxf(m, 1e-30f) / 127.f;
    const float inv = 127.f / fmaxf(m, 1e-30f);
    i8* qr = q + (size_t)r * E;
#pragma unroll
    for (int u = 0; u < 8; ++u) {
        int a0 = (int)rintf(v[u].x * inv);
        int a1 = (int)rintf(v[u].y * inv);
        int a2 = (int)rintf(v[u].z * inv);
        int a3 = (int)rintf(v[u].w * inv);
        u32 pk = ((u32)(a0 & 0xff)) | ((u32)(a1 & 0xff) << 8) |
                 ((u32)(a2 & 0xff) << 16) | ((u32)(a3 & 0xff) << 24);
        *(u32*)(qr + u * 256 + l * 4) = pk;
    }
    if (l == 0) scales[r] = scale;
}

// W_outT[e][d] = W_out[d][e]
__global__ void k_transpose_wout(const float* __restrict__ wout, float* __restrict__ woutT) {
    int o = blockIdx.x * blockDim.x + threadIdx.x;
    if (o >= E * 128) return;
    int e = o >> 7, d = o & 127;
    woutT[o] = wout[d * E + e];
}

__global__ void k_bias(const float* __restrict__ bih0, const float* __restrict__ bhh0,
                       const float* __restrict__ bih1, const float* __restrict__ bhh1,
                       float* __restrict__ bias0, float* __restrict__ bias1) {
    int r = blockIdx.x * blockDim.x + threadIdx.x;
    if (r >= 4 * E) return;
    bias0[r] = bih0[r] + bhh0[r];
    bias1[r] = bih1[r] + bhh1[r];
}

__global__ void k_init(const float* __restrict__ lat, float* __restrict__ hist0,
                       float* __restrict__ h0buf0, float* __restrict__ c0,
                       float* __restrict__ c1) {
    int i = blockIdx.x * blockDim.x + threadIdx.x;
    if (i >= E) return;
    float v = lat[i];
    hist0[i] = v;
    h0buf0[i] = v;
    c0[i] = 0.f;
    c1[i] = 0.f;
}

// ---------------- LSTM epilogue (shared) ----------------
__device__ __forceinline__ void lstm_epilogue(int e, const float g[4],
                                              const float* __restrict__ bias,
                                              float* __restrict__ c,
                                              float* __restrict__ hout) {
    float gi = g[0] + bias[e];
    float gf = g[1] + bias[E + e];
    float gg = g[2] + bias[2 * E + e];
    float go = g[3] + bias[3 * E + e];
    float i = 1.f / (1.f + expf(-gi));
    float f = 1.f / (1.f + expf(-gf));
    float gv = tanhf(gg);
    float o = 1.f / (1.f + expf(-go));
    float cn = fmaf(f, c[e], i * gv);
    c[e] = cn;
    hout[e] = o * tanhf(cn);
}

// ---------------- per-step kernels ----------------

// x[d] = b_out[d] + dot(W_out[d][:], h)   (W_out fp16); 128 blocks x 64
__global__ __launch_bounds__(64) void k_xh(const u16* __restrict__ wout,
                                           const float* __restrict__ h,
                                           const float* __restrict__ bout,
                                           float* __restrict__ x) {
    const int d = blockIdx.x;
    const int l = threadIdx.x;
    const u16* w = wout + (size_t)d * E;
    float acc = 0.f;
#pragma unroll
    for (int v = 0; v < 4; ++v) {
        int idx = v * 512 + l * 8;
        uint4 u = *(const uint4*)(w + idx);
        float4 r0 = *(const float4*)(h + idx);
        float4 r1 = *(const float4*)(h + idx + 4);
        acc = fmaf(hlo(u.x), r0.x, acc);
        acc = fmaf(hhi(u.x), r0.y, acc);
        acc = fmaf(hlo(u.y), r0.z, acc);
        acc = fmaf(hhi(u.y), r0.w, acc);
        acc = fmaf(hlo(u.z), r1.x, acc);
        acc = fmaf(hhi(u.z), r1.y, acc);
        acc = fmaf(hlo(u.w), r1.z, acc);
        acc = fmaf(hhi(u.w), r1.w, acc);
    }
#pragma unroll
    for (int off = 32; off > 0; off >>= 1) acc += __shfl_xor(acc, off);
    if (l == 0) x[d] = acc + bout[d];
}

// layer 0, K-split: 2048 blocks x 128 threads; wave w owns K-half [w*1024,(w+1)*1024)
__global__ __launch_bounds__(128) void k_l0q(
    const u16* __restrict__ Wih0, const float* __restrict__ x,
    const i8* __restrict__ Qhh0, const float* __restrict__ sHH0,
    const float* __restrict__ h0in,
    const float* __restrict__ bias, float* __restrict__ c, float* __restrict__ hout) {
    const int e = blockIdx.x;
    const int tid = threadIdx.x;
    const int w = tid >> 6, l = tid & 63;
    const int base = w * 1024 + l * 16;

    // this wave's input half -> regs
    float4 rh[4];
    rh[0] = *(const float4*)(h0in + base);
    rh[1] = *(const float4*)(h0in + base + 4);
    rh[2] = *(const float4*)(h0in + base + 8);
    rh[3] = *(const float4*)(h0in + base + 12);
    float2 rx = make_float2(0.f, 0.f);
    if (w == 0) rx = *(const float2*)(x + l * 2);

    // hoist ALL weight loads (deep in-flight queue)
    int rows[4];
    uint4 wh[4];
    u32 wix[4] = {0, 0, 0, 0};
#pragma unroll
    for (int q = 0; q < 4; ++q) {
        rows[q] = q * E + e;
        wh[q] = *(const uint4*)(Qhh0 + (size_t)rows[q] * E + base);
    }
    if (w == 0) {
#pragma unroll
        for (int q = 0; q < 4; ++q)
            wix[q] = *(const u32*)(Wih0 + (size_t)rows[q] * 128 + l * 2);
    }

    __shared__ float gl[8];
#pragma unroll
    for (int q = 0; q < 4; ++q) {
        float acc = 0.f;
        acc = dot4(i8x4_to_f4(wh[q].x), rh[0], acc);
        acc = dot4(i8x4_to_f4(wh[q].y), rh[1], acc);
        acc = dot4(i8x4_to_f4(wh[q].z), rh[2], acc);
        acc = dot4(i8x4_to_f4(wh[q].w), rh[3], acc);
        float t = acc * sHH0[rows[q]];
        if (w == 0) t += hlo(wix[q]) * rx.x + hhi(wix[q]) * rx.y;
        t = wred(t);
        if (l == 0) gl[w * 4 + q] = t;
    }
    __syncthreads();
    if (tid == 0) {
        float g[4] = {gl[0] + gl[4], gl[1] + gl[5], gl[2] + gl[6], gl[3] + gl[7]};
        lstm_epilogue(e, g, bias, c, hout);
    }
}

// layer 1, K-split: 2048 blocks x 128 threads
__global__ __launch_bounds__(128) void k_l1q(
    const i8* __restrict__ Qa, const float* __restrict__ sA,
    const float* __restrict__ ina,
    const i8* __restrict__ Qb, const float* __restrict__ sB,
    const float* __restrict__ inb,
    const float* __restrict__ bias, float* __restrict__ c, float* __restrict__ hout) {
    const int e = blockIdx.x;
    const int tid = threadIdx.x;
    const int w = tid >> 6, l = tid & 63;
    const int base = w * 1024 + l * 16;

    float4 ra[4], rb[4];
    ra[0] = *(const float4*)(ina + base);
    ra[1] = *(const float4*)(ina + base + 4);
    ra[2] = *(const float4*)(ina + base + 8);
    ra[3] = *(const float4*)(ina + base + 12);
    rb[0] = *(const float4*)(inb + base);
    rb[1] = *(const float4*)(inb + base + 4);
    rb[2] = *(const float4*)(inb + base + 8);
    rb[3] = *(const float4*)(inb + base + 12);

    int rows[4];
    uint4 wa[4], wb[4];
#pragma unroll
    for (int q = 0; q < 4; ++q) {
        rows[q] = q * E + e;
        wa[q] = *(const uint4*)(Qa + (size_t)rows[q] * E + base);
        wb[q] = *(const uint4*)(Qb + (size_t)rows[q] * E + base);
    }

    __shared__ float gl[8];
#pragma unroll
    for (int q = 0; q < 4; ++q) {
        float acca = 0.f, accb = 0.f;
        acca = dot4(i8x4_to_f4(wa[q].x), ra[0], acca);
        acca = dot4(i8x4_to_f4(wa[q].y), ra[1], acca);
        acca = dot4(i8x4_to_f4(wa[q].z), ra[2], acca);
        acca = dot4(i8x4_to_f4(wa[q].w), ra[3], acca);
        accb = dot4(i8x4_to_f4(wb[q].x), rb[0], accb);
        accb = dot4(i8x4_to_f4(wb[q].y), rb[1], accb);
        accb = dot4(i8x4_to_f4(wb[q].z), rb[2], accb);
        accb = dot4(i8x4_to_f4(wb[q].w), rb[3], accb);
        float t = acca * sA[rows[q]] + accb * sB[rows[q]];
        t = wred(t);
        if (l == 0) gl[w * 4 + q] = t;
    }
    __syncthreads();
    if (tid == 0) {
        float g[4] = {gl[0] + gl[4], gl[1] + gl[5], gl[2] + gl[6], gl[3] + gl[7]};
        lstm_epilogue(e, g, bias, c, hout);
    }
}

// ---------------- final output GEMM ----------------
__global__ __launch_bounds__(128) void k_out(const float* __restrict__ woutT,
                                             const float* __restrict__ hist,
                                             const float* __restrict__ bout,
                                             float* __restrict__ out) {
    __shared__ float h[E];
    int t = blockIdx.x, d = threadIdx.x;
    for (int i = d; i < E; i += 128) h[i] = hist[(size_t)t * E + i];
    __syncthreads();
    float acc0 = bout[d], acc1 = 0.f;
#pragma unroll 4
    for (int k = 0; k < E; k += 2) {
        acc0 = fmaf(woutT[k * 128 + d], h[k], acc0);
        acc1 = fmaf(woutT[(k + 1) * 128 + d], h[k + 1], acc1);
    }
    out[t * 128 + d] = acc0 + acc1;
}

extern "C" void kernel_launch(void* const* d_in, const int* in_sizes, int n_in,
                              void* d_out, int out_size, void* d_ws, size_t ws_size,
                              hipStream_t stream) {
    const float* lat = (const float*)d_in[0];
    const float* wih0 = (const float*)d_in[1];
    const float* whh0 = (const float*)d_in[2];
    const float* bih0 = (const float*)d_in[3];
    const float* bhh0 = (const float*)d_in[4];
    const float* wih1 = (const float*)d_in[5];
    const float* whh1 = (const float*)d_in[6];
    const float* bih1 = (const float*)d_in[7];
    const float* bhh1 = (const float*)d_in[8];
    const float* wout = (const float*)d_in[9];
    const float* bout = (const float*)d_in[10];

    const size_t QB = (size_t)4 * E * E;  // 16.78 MB per int8 matrix
    char* p = (char*)d_ws;
    i8* Qhh0 = (i8*)p;  p += QB;
    i8* Qih1 = (i8*)p;  p += QB;
    i8* Qhh1 = (i8*)p;  p += QB;
    float* sHH0 = (float*)p; p += (size_t)4 * E * 4;
    float* sIH1 = (float*)p; p += (size_t)4 * E * 4;
    float* sHH1 = (float*)p; p += (size_t)4 * E * 4;
    u16* Wih0h = (u16*)p; p += (size_t)4 * E * 128 * 2;
    u16* Wouth = (u16*)p; p += (size_t)128 * E * 2;
    float* woutT = (float*)p; p += (size_t)E * 128 * 4;
    float* bias0 = (float*)p; p += (size_t)4 * E * 4;
    float* bias1 = (float*)p; p += (size_t)4 * E * 4;
    float* hist = (float*)p;  p += (size_t)T_STEPS * E * 4;
    float* h0buf = (float*)p; p += (size_t)2 * E * 4;
    float* c0 = (float*)p;    p += (size_t)E * 4;
    float* c1 = (float*)p;    p += (size_t)E * 4;
    float* xbuf = (float*)p;  p += (size_t)128 * 4;

    k_quant<<<4 * E, 64, 0, stream>>>(whh0, Qhh0, sHH0);
    k_quant<<<4 * E, 64, 0, stream>>>(wih1, Qih1, sIH1);
    k_quant<<<4 * E, 64, 0, stream>>>(whh1, Qhh1, sHH1);
    const int n8i = 4 * E * 128 / 8;
    k_cvt_f16<<<(n8i + 255) / 256, 256, 0, stream>>>(wih0, Wih0h, n8i);
    const int n8o = 128 * E / 8;
    k_cvt_f16<<<(n8o + 255) / 256, 256, 0, stream>>>(wout, Wouth, n8o);
    k_transpose_wout<<<(E * 128 + 255) / 256, 256, 0, stream>>>(wout, woutT);
    k_bias<<<(4 * E + 255) / 256, 256, 0, stream>>>(bih0, bhh0, bih1, bhh1, bias0, bias1);
    k_init<<<(E + 255) / 256, 256, 0, stream>>>(lat, hist, h0buf, c0, c1);

    for (int s = 1; s < T_STEPS; ++s) {
        const float* h1p = hist + (size_t)(s - 1) * E;
        const float* h0p = h0buf + (size_t)((s - 1) & 1) * E;
        float* h0n = h0buf + (size_t)(s & 1) * E;
        float* h1n = hist + (size_t)s * E;
        k_xh<<<128, 64, 0, stream>>>(Wouth, h1p, bout, xbuf);
        k_l0q<<<E, 128, 0, stream>>>(Wih0h, xbuf, Qhh0, sHH0, h0p, bias0, c0, h0n);
        k_l1q<<<E, 128, 0, stream>>>(Qih1, sIH1, h0n, Qhh1, sHH1, h1p, bias1, c1, h1n);
    }

    k_out<<<T_STEPS, 128, 0, stream>>>(woutT, hist, bout, (float*)d_out);
}

// Round 12
// 9568.594 us; speedup vs baseline: 5.9631x; 1.1320x over previous
//
#include <hip/hip_runtime.h>
#include <hip/hip_fp16.h>

typedef unsigned short u16;
typedef unsigned int u32;
typedef signed char i8;

#define E 2048
#define T_STEPS 512

// ---------------- helpers ----------------
// dequant 8 int4 (offset-8 nibbles) from one u32 against 8 h-values
__device__ __forceinline__ float dot8i4(u32 v, float4 a, float4 b, float acc) {
    acc = fmaf((float)((int)(v & 15u) - 8), a.x, acc);
    acc = fmaf((float)((int)((v >> 4) & 15u) - 8), a.y, acc);
    acc = fmaf((float)((int)((v >> 8) & 15u) - 8), a.z, acc);
    acc = fmaf((float)((int)((v >> 12) & 15u) - 8), a.w, acc);
    acc = fmaf((float)((int)((v >> 16) & 15u) - 8), b.x, acc);
    acc = fmaf((float)((int)((v >> 20) & 15u) - 8), b.y, acc);
    acc = fmaf((float)((int)((v >> 24) & 15u) - 8), b.z, acc);
    acc = fmaf((float)((int)(v >> 28) - 8), b.w, acc);
    return acc;
}
__device__ __forceinline__ float wred(float t) {
#pragma unroll
    for (int off = 32; off > 0; off >>= 1) t += __shfl_xor(t, off);
    return t;
}
__device__ __forceinline__ float sigm(float v) { return 1.f / (1.f + expf(-v)); }

// ---------------- prep kernels ----------------

// W_comb[r][c] = sum_k W_ih0[r][k] * W_out[k][c]  (fp32; 8192 x 2048)
__global__ __launch_bounds__(256) void k_wcomb(const float* __restrict__ wih0,
                                               const float* __restrict__ wout,
                                               float* __restrict__ wc) {
    __shared__ float a[8 * 128];
    int r0 = blockIdx.y * 8;
    int c = blockIdx.x * 256 + threadIdx.x;
    for (int i = threadIdx.x; i < 8 * 128; i += 256) a[i] = wih0[r0 * 128 + i];
    __syncthreads();
    float acc[8] = {0.f, 0.f, 0.f, 0.f, 0.f, 0.f, 0.f, 0.f};
    for (int k = 0; k < 128; ++k) {
        float b = wout[k * E + c];
#pragma unroll
        for (int j = 0; j < 8; ++j) acc[j] = fmaf(a[j * 128 + k], b, acc[j]);
    }
#pragma unroll
    for (int j = 0; j < 8; ++j) wc[(size_t)(r0 + j) * E + c] = acc[j];
}

// per-row int4 quantization: one wave per row; row -> 1024 B (nibble = q+8)
__global__ __launch_bounds__(64) void k_quant4(const float* __restrict__ in,
                                               u32* __restrict__ q,
                                               float* __restrict__ scales) {
    const int r = blockIdx.x;
    const int l = threadIdx.x;
    const float* row = in + (size_t)r * E + l * 32;
    float4 v[8];
    float m = 0.f;
#pragma unroll
    for (int j = 0; j < 8; ++j) {
        v[j] = *(const float4*)(row + j * 4);
        m = fmaxf(m, fmaxf(fmaxf(fabsf(v[j].x), fabsf(v[j].y)),
                           fmaxf(fabsf(v[j].z), fabsf(v[j].w))));
    }
#pragma unroll
    for (int off = 32; off > 0; off >>= 1) m = fmaxf(m, __shfl_xor(m, off));
    m = fmaxf(m, 1e-30f);
    const float inv = 7.f / m;
    float fv[32];
#pragma unroll
    for (int j = 0; j < 8; ++j) {
        fv[4 * j] = v[j].x;
        fv[4 * j + 1] = v[j].y;
        fv[4 * j + 2] = v[j].z;
        fv[4 * j + 3] = v[j].w;
    }
    u32 pk[4] = {0u, 0u, 0u, 0u};
#pragma unroll
    for (int i = 0; i < 32; ++i) {
        int qv = (int)rintf(fv[i] * inv);
        qv = qv < -7 ? -7 : (qv > 7 ? 7 : qv);
        pk[i >> 3] |= ((u32)(qv + 8)) << (4 * (i & 7));
    }
    ((uint4*)(q + (size_t)r * 256))[l] = make_uint4(pk[0], pk[1], pk[2], pk[3]);
    if (l == 0) scales[r] = m / 7.f;
}

// W_outT[e][d] = W_out[d][e]
__global__ void k_transpose_wout(const float* __restrict__ wout, float* __restrict__ woutT) {
    int o = blockIdx.x * blockDim.x + threadIdx.x;
    if (o >= E * 128) return;
    int e = o >> 7, d = o & 127;
    woutT[o] = wout[d * E + e];
}

// bcomb[r] = b_ih0[r]+b_hh0[r]+dot(W_ih0[r],b_out);  bias1[r] = b_ih1[r]+b_hh1[r]
__global__ void k_bcomb(const float* __restrict__ wih0, const float* __restrict__ bout,
                        const float* __restrict__ bih0, const float* __restrict__ bhh0,
                        const float* __restrict__ bih1, const float* __restrict__ bhh1,
                        float* __restrict__ bcomb, float* __restrict__ bias1) {
    int r = blockIdx.x * blockDim.x + threadIdx.x;
    if (r >= 4 * E) return;
    float acc = bih0[r] + bhh0[r];
    const float* w = wih0 + (size_t)r * 128;
#pragma unroll 8
    for (int k = 0; k < 128; ++k) acc = fmaf(w[k], bout[k], acc);
    bcomb[r] = acc;
    bias1[r] = bih1[r] + bhh1[r];
}

// hist[0] = lat, h0buf slot0 = lat, c0 = c1 = 0
__global__ void k_init(const float* __restrict__ lat, float* __restrict__ hist0,
                       float* __restrict__ h0buf0, float* __restrict__ c0,
                       float* __restrict__ c1) {
    int i = blockIdx.x * blockDim.x + threadIdx.x;
    if (i >= E) return;
    float v = lat[i];
    hist0[i] = v;
    h0buf0[i] = v;
    c0[i] = 0.f;
    c1[i] = 0.f;
}

// ---------------- LSTM epilogue ----------------
__device__ __forceinline__ void lstm_epilogue(int e, const float g[4],
                                              const float* __restrict__ bias,
                                              float* __restrict__ c,
                                              float* __restrict__ hout) {
    float gi = g[0] + bias[e];
    float gf = g[1] + bias[E + e];
    float gg = g[2] + bias[2 * E + e];
    float go = g[3] + bias[3 * E + e];
    float cn = fmaf(sigm(gf), c[e], sigm(gi) * tanhf(gg));
    c[e] = cn;
    hout[e] = sigm(go) * tanhf(cn);
}

// ---------------- per-step kernels (single wave, 64 thr; int4 weights) ----------------
// layer 0: gates = Qc@h1(s-1) + Qh0@h0(s-1) + bcomb
__global__ __launch_bounds__(64) void k_l0q4(
    const u32* __restrict__ Qc, const float* __restrict__ sC,
    const float* __restrict__ h1in,
    const u32* __restrict__ Qh0, const float* __restrict__ sH0,
    const float* __restrict__ h0in,
    const float* __restrict__ bias, float* __restrict__ c, float* __restrict__ hout) {
    const int e = blockIdx.x;
    const int l = threadIdx.x;
    const int eb = l * 32;

    float4 r1[8], r0[8];
#pragma unroll
    for (int j = 0; j < 8; ++j) {
        r1[j] = *(const float4*)(h1in + eb + j * 4);
        r0[j] = *(const float4*)(h0in + eb + j * 4);
    }
    uint4 wc[4], wh[4];
#pragma unroll
    for (int q = 0; q < 4; ++q) {
        const size_t row = (size_t)q * E + e;
        wc[q] = ((const uint4*)(Qc + row * 256))[l];
        wh[q] = ((const uint4*)(Qh0 + row * 256))[l];
    }

    float g[4];
#pragma unroll
    for (int q = 0; q < 4; ++q) {
        const int row = q * E + e;
        float aC = 0.f, aH = 0.f;
        aC = dot8i4(wc[q].x, r1[0], r1[1], aC);
        aC = dot8i4(wc[q].y, r1[2], r1[3], aC);
        aC = dot8i4(wc[q].z, r1[4], r1[5], aC);
        aC = dot8i4(wc[q].w, r1[6], r1[7], aC);
        aH = dot8i4(wh[q].x, r0[0], r0[1], aH);
        aH = dot8i4(wh[q].y, r0[2], r0[3], aH);
        aH = dot8i4(wh[q].z, r0[4], r0[5], aH);
        aH = dot8i4(wh[q].w, r0[6], r0[7], aH);
        g[q] = wred(aC * sC[row] + aH * sH0[row]);
    }
    if (l == 0) lstm_epilogue(e, g, bias, c, hout);
}

// layer 1: gates = Qi1@h0(s) + Qh1@h1(s-1) + bias1
__global__ __launch_bounds__(64) void k_l1q4(
    const u32* __restrict__ Qi1, const float* __restrict__ sI1,
    const float* __restrict__ h0in,
    const u32* __restrict__ Qh1, const float* __restrict__ sH1,
    const float* __restrict__ h1in,
    const float* __restrict__ bias, float* __restrict__ c, float* __restrict__ hout) {
    const int e = blockIdx.x;
    const int l = threadIdx.x;
    const int eb = l * 32;

    float4 r0[8], r1[8];
#pragma unroll
    for (int j = 0; j < 8; ++j) {
        r0[j] = *(const float4*)(h0in + eb + j * 4);
        r1[j] = *(const float4*)(h1in + eb + j * 4);
    }
    uint4 wi[4], wh[4];
#pragma unroll
    for (int q = 0; q < 4; ++q) {
        const size_t row = (size_t)q * E + e;
        wi[q] = ((const uint4*)(Qi1 + row * 256))[l];
        wh[q] = ((const uint4*)(Qh1 + row * 256))[l];
    }

    float g[4];
#pragma unroll
    for (int q = 0; q < 4; ++q) {
        const int row = q * E + e;
        float aI = 0.f, aH = 0.f;
        aI = dot8i4(wi[q].x, r0[0], r0[1], aI);
        aI = dot8i4(wi[q].y, r0[2], r0[3], aI);
        aI = dot8i4(wi[q].z, r0[4], r0[5], aI);
        aI = dot8i4(wi[q].w, r0[6], r0[7], aI);
        aH = dot8i4(wh[q].x, r1[0], r1[1], aH);
        aH = dot8i4(wh[q].y, r1[2], r1[3], aH);
        aH = dot8i4(wh[q].z, r1[4], r1[5], aH);
        aH = dot8i4(wh[q].w, r1[6], r1[7], aH);
        g[q] = wred(aI * sI1[row] + aH * sH1[row]);
    }
    if (l == 0) lstm_epilogue(e, g, bias, c, hout);
}

// ---------------- final output GEMM: out[t] = Wout @ hist[t] + bout ----------------
__global__ __launch_bounds__(128) void k_out(const float* __restrict__ woutT,
                                             const float* __restrict__ hist,
                                             const float* __restrict__ bout,
                                             float* __restrict__ out) {
    __shared__ float h[E];
    int t = blockIdx.x, d = threadIdx.x;
    for (int i = d; i < E; i += 128) h[i] = hist[(size_t)t * E + i];
    __syncthreads();
    float acc0 = bout[d], acc1 = 0.f;
#pragma unroll 4
    for (int k = 0; k < E; k += 2) {
        acc0 = fmaf(woutT[k * 128 + d], h[k], acc0);
        acc1 = fmaf(woutT[(k + 1) * 128 + d], h[k + 1], acc1);
    }
    out[t * 128 + d] = acc0 + acc1;
}

extern "C" void kernel_launch(void* const* d_in, const int* in_sizes, int n_in,
                              void* d_out, int out_size, void* d_ws, size_t ws_size,
                              hipStream_t stream) {
    const float* lat = (const float*)d_in[0];
    const float* wih0 = (const float*)d_in[1];
    const float* whh0 = (const float*)d_in[2];
    const float* bih0 = (const float*)d_in[3];
    const float* bhh0 = (const float*)d_in[4];
    const float* wih1 = (const float*)d_in[5];
    const float* whh1 = (const float*)d_in[6];
    const float* bih1 = (const float*)d_in[7];
    const float* bhh1 = (const float*)d_in[8];
    const float* wout = (const float*)d_in[9];
    const float* bout = (const float*)d_in[10];

    const size_t Q4B = (size_t)4 * E * E / 2;  // 8.39 MB per int4 matrix
    char* p = (char*)d_ws;
    u32* Qc = (u32*)p;   p += Q4B;
    u32* Qh0 = (u32*)p;  p += Q4B;
    u32* Qi1 = (u32*)p;  p += Q4B;
    u32* Qh1 = (u32*)p;  p += Q4B;
    float* sC = (float*)p;  p += (size_t)4 * E * 4;
    float* sH0 = (float*)p; p += (size_t)4 * E * 4;
    float* sI1 = (float*)p; p += (size_t)4 * E * 4;
    float* sH1 = (float*)p; p += (size_t)4 * E * 4;
    float* WcF = (float*)p; p += (size_t)4 * E * E * 4;  // 67 MB temp
    float* woutT = (float*)p; p += (size_t)E * 128 * 4;
    float* bcomb = (float*)p; p += (size_t)4 * E * 4;
    float* bias1 = (float*)p; p += (size_t)4 * E * 4;
    float* hist = (float*)p;  p += (size_t)T_STEPS * E * 4;
    float* h0buf = (float*)p; p += (size_t)2 * E * 4;
    float* c0 = (float*)p;    p += (size_t)E * 4;
    float* c1 = (float*)p;    p += (size_t)E * 4;

    k_wcomb<<<dim3(8, 1024), 256, 0, stream>>>(wih0, wout, WcF);
    k_quant4<<<4 * E, 64, 0, stream>>>(WcF, Qc, sC);
    k_quant4<<<4 * E, 64, 0, stream>>>(whh0, Qh0, sH0);
    k_quant4<<<4 * E, 64, 0, stream>>>(wih1, Qi1, sI1);
    k_quant4<<<4 * E, 64, 0, stream>>>(whh1, Qh1, sH1);
    k_transpose_wout<<<(E * 128 + 255) / 256, 256, 0, stream>>>(wout, woutT);
    k_bcomb<<<(4 * E + 255) / 256, 256, 0, stream>>>(wih0, bout, bih0, bhh0, bih1, bhh1,
                                                     bcomb, bias1);
    k_init<<<(E + 255) / 256, 256, 0, stream>>>(lat, hist, h0buf, c0, c1);

    for (int s = 1; s < T_STEPS; ++s) {
        const float* h1p = hist + (size_t)(s - 1) * E;
        const float* h0p = h0buf + (size_t)((s - 1) & 1) * E;
        float* h0n = h0buf + (size_t)(s & 1) * E;
        float* h1n = hist + (size_t)s * E;
        k_l0q4<<<E, 64, 0, stream>>>(Qc, sC, h1p, Qh0, sH0, h0p, bcomb, c0, h0n);
        k_l1q4<<<E, 64, 0, stream>>>(Qi1, sI1, h0n, Qh1, sH1, h1p, bias1, c1, h1n);
    }

    k_out<<<T_STEPS, 128, 0, stream>>>(woutT, hist, bout, (float*)d_out);
}